// Round 7
// baseline (27313.242 us; speedup 1.0000x reference)
//
#include <hip/hip_runtime.h>

typedef unsigned short u16;
typedef unsigned int u32;
typedef unsigned long long u64;
typedef _Float16 f16;
typedef __attribute__((ext_vector_type(8))) _Float16 f16x8;
typedef __attribute__((ext_vector_type(4))) float f32x4;

#define TT 512
#define DD 64
#define SC 2048.0f
#define ISC (1.0f / 2048.0f)

// Activation buffers (H1/H2): f16 hi/lo-split pairs, MFMA-fragment layout:
// [mtile(16)][ks(32: 0-15 hi, 16-31 lo*2^11)][1KB frag]. Weight B-frags split
// into H and L (L pre-scaled by 2^11; true value = H + L/2^11).
//
// TWO DATA-PATH MODES, chosen at runtime after XCD discovery:
//  LOCAL (cnt[xcc]==32 for all 8 XCDs): all 16 column-blocks of an mtile sit
//   on one XCD -> H1/H2 producer-consumer edges are XCD-local. Loads use
//   sc0-only (L1-bypass, L2-cached, 16B wide); stores plain (L1 write-through
//   -> L2). Barrier is per-XCD (no root hop). 8 XCDs run independently.
//  FALLBACK: R6-proven path — agent-scope (MALL) ldc/stc + global barrier.
// z1/z2 flags + barrier always via MALL atomics (tiny). Weights/x/bias plain
// cached -> L2-resident. c1/c2/h2m same-thread-private -> plain cached.
struct WS {
  f16 *PB1aH, *PB1aL, *PB1bH, *PB1bL, *PB1xH, *PB1xL;
  f16 *PB2aH, *PB2aL, *PB2bH, *PB2bL, *PBo;
  float *wz1, *wz2, *b1f, *b2f, *bof;
  f16 *H1[2], *H2[2];
  float *c1, *c2, *h2m;
  float *z1[2], *z2[2];
  int *bar;   // [grp*32] cnts, [256] root, [288+grp*32] gens, [544+xcc*8] regcnt
  int *flag;  // 1 = inputs are float32, 0 = inputs are bf16
};

__device__ __forceinline__ float bf2f(u16 u) { return __uint_as_float(((u32)u) << 16); }
__device__ __forceinline__ u16 f2bf(float f) {
  u32 u = __float_as_uint(f);
  u += 0x7fffu + ((u >> 16) & 1u);
  return (u16)(u >> 16);
}
__device__ __forceinline__ float ldw(const void* p, size_t i, int f32) {
  return f32 ? ((const float*)p)[i] : bf2f(((const u16*)p)[i]);
}
__device__ __forceinline__ float sigm(float x) { return 1.0f / (1.0f + expf(-x)); }
__device__ __forceinline__ f16x8 ldf(const f16* p) { return *(const f16x8*)p; }

// ---- agent-scope (MALL) accessors: correct across XCDs, slow (8B grain) ----
__device__ __forceinline__ f16x8 ldc(const f16* p) {
  union { u64 u[2]; f16x8 v; } r;
  r.u[0] = __hip_atomic_load((const u64*)p,     __ATOMIC_RELAXED, __HIP_MEMORY_SCOPE_AGENT);
  r.u[1] = __hip_atomic_load((const u64*)p + 1, __ATOMIC_RELAXED, __HIP_MEMORY_SCOPE_AGENT);
  return r.v;
}
__device__ __forceinline__ void stc16(f16* p, f16 v) {
  u16 b;
  __builtin_memcpy(&b, &v, 2);
  __hip_atomic_store((u16*)p, b, __ATOMIC_RELAXED, __HIP_MEMORY_SCOPE_AGENT);
}
__device__ __forceinline__ float ldcf(const float* p) {
  return __hip_atomic_load(p, __ATOMIC_RELAXED, __HIP_MEMORY_SCOPE_AGENT);
}
__device__ __forceinline__ void stcf(float* p, float v) {
  __hip_atomic_store(p, v, __ATOMIC_RELAXED, __HIP_MEMORY_SCOPE_AGENT);
}

// ---- mode-conditional 4x16B load: LOCAL -> sc0 (L1-bypass, L2-hit, wide);
//      FALLBACK -> MALL ldc. Outputs early-clobber (loads complete OOO). ----
__device__ __forceinline__ void ld4a(const f16* p0, const f16* p1,
                                     const f16* p2, const f16* p3,
                                     f16x8& r0, f16x8& r1, f16x8& r2, f16x8& r3,
                                     int lok)
{
  if (lok) {
    asm volatile(
      "global_load_dwordx4 %0, %4, off sc0\n\t"
      "global_load_dwordx4 %1, %5, off sc0\n\t"
      "global_load_dwordx4 %2, %6, off sc0\n\t"
      "global_load_dwordx4 %3, %7, off sc0\n\t"
      "s_waitcnt vmcnt(0)"
      : "=&v"(r0), "=&v"(r1), "=&v"(r2), "=&v"(r3)
      : "v"(p0), "v"(p1), "v"(p2), "v"(p3)
      : "memory");
  } else {
    r0 = ldc(p0); r1 = ldc(p1); r2 = ldc(p2); r3 = ldc(p3);
  }
}
// mode-conditional 2B store: LOCAL -> plain (write-through L1 -> local L2)
__device__ __forceinline__ void st2a(f16* p, f16 v, int lok) {
  if (lok) *p = v;
  else stc16(p, v);
}

__device__ __forceinline__ double shfl_down_dbl(double v, int off) {
  const int lo = __shfl_down(__double2loint(v), off);
  const int hi = __shfl_down(__double2hiint(v), off);
  return __hiloint2double(hi, lo);
}

#define MFMA(a, b, c) __builtin_amdgcn_mfma_f32_16x16x32_f16(a, b, c, 0, 0, 0)

// -------- barrier: MONOTONIC, relaxed-only, epoch k (1-based) ---------------
// lok=0: two-level global (32/group -> root -> 8 gens)  [R5/R6-proven]
// lok=1: per-XCD (grp = xcc): 32 arrivals bump own gen directly, no root.
// Group-count invariant: every group line receives exactly 32 adds per epoch
// under BOTH partitions (bid&7 and xcc), so thresholds 32*k stay consistent.
__device__ __forceinline__ void gridbar(int* __restrict__ bar, int grp, int k, int lok)
{
  __syncthreads();
  if (threadIdx.x == 0) {
    int* myc   = bar + grp * 32;
    int* gens  = bar + 288;
    int* mygen = gens + grp * 32;
    if (__hip_atomic_fetch_add(myc, 1, __ATOMIC_RELAXED,
                               __HIP_MEMORY_SCOPE_AGENT) + 1 == 32 * k) {
      if (lok) {
        __hip_atomic_fetch_add(mygen, 1, __ATOMIC_RELAXED, __HIP_MEMORY_SCOPE_AGENT);
      } else if (__hip_atomic_fetch_add(bar + 256, 1, __ATOMIC_RELAXED,
                                        __HIP_MEMORY_SCOPE_AGENT) + 1 == 8 * k) {
#pragma unroll
        for (int i = 0; i < 8; ++i)
          __hip_atomic_fetch_add(gens + i * 32, 1, __ATOMIC_RELAXED,
                                 __HIP_MEMORY_SCOPE_AGENT);
      }
    }
    const long long t0 = (long long)__builtin_amdgcn_s_memrealtime();
    while (__hip_atomic_load(mygen, __ATOMIC_RELAXED,
                             __HIP_MEMORY_SCOPE_AGENT) < k) {
      __builtin_amdgcn_s_sleep(2);
      if ((long long)__builtin_amdgcn_s_memrealtime() - t0 > 2000000LL) break;
    }
  }
  __syncthreads();
}

// ---------------- dtype detection ----------------
__global__ void detect_kernel(const u16* __restrict__ x, int* __restrict__ flag)
{
  int tid = threadIdx.x;  // 64 threads
  int cnt = 0;
  for (int i = tid; i < 8192; i += 64) {
    int e = (x[i] >> 7) & 0xFF;
    cnt += (e >= 0xC0 || (e != 0 && e < 0x30)) ? 1 : 0;
  }
#pragma unroll
  for (int off = 32; off; off >>= 1) cnt += __shfl_down(cnt, off);
  if (tid == 0) *flag = (cnt > 100) ? 1 : 0;
}

// ---------------- prologue: weight packing ----------------
__device__ __forceinline__ void packGate(const void* __restrict__ U,
                                         f16* __restrict__ dstH, f16* __restrict__ dstL,
                                         int g, int KS, int F32) {
  int lane = g & 63;
  int rest = g >> 6;
  int t2 = rest & 1; rest >>= 1;
  int ks = rest % KS;
  int J  = rest / KS;
  int q = lane >> 4, n = lane & 15;
  int j = J * 8 + (n & 7);
  int c = (t2 * 2 + (n >> 3)) * 512 + j;
  int kb = ks * 32 + q * 8;
  f16 vh[8], vl[8];
#pragma unroll
  for (int i = 0; i < 8; ++i) {
    float v = ldw(U, (size_t)(kb + i) * 2049 + c, F32);
    f16 h = (f16)v;
    vh[i] = h;
    vl[i] = (f16)((v - (float)h) * SC);
  }
  *(f16x8*)(dstH + (size_t)g * 8) = *(f16x8*)vh;
  *(f16x8*)(dstL + (size_t)g * 8) = *(f16x8*)vl;
}

#define NPACK (4 * 131072 + 16384 + 8192 + 2112 + 2048 + 2049 + 2049 + 64)

__global__ __launch_bounds__(256) void pack_kernel(
    const void* __restrict__ U11_1, const void* __restrict__ U21_1,
    const void* __restrict__ W01_1, const void* __restrict__ bias1,
    const void* __restrict__ U11_2, const void* __restrict__ W01_2,
    const void* __restrict__ bias2, const void* __restrict__ l1W,
    const void* __restrict__ l1b, const void* __restrict__ l2W,
    const void* __restrict__ l2b, WS w)
{
  const int F32 = *w.flag;
  int gid = blockIdx.x * 256 + threadIdx.x;
  const int NG = 131072;
  if (gid < NG) { packGate(U11_1, w.PB1aH, w.PB1aL, gid, 16, F32); return; }
  gid -= NG;
  if (gid < NG) { packGate(U21_1, w.PB1bH, w.PB1bL, gid, 16, F32); return; }
  gid -= NG;
  if (gid < NG) { packGate(U11_2, w.PB2aH, w.PB2aL, gid, 16, F32); return; }
  gid -= NG;
  if (gid < NG) { packGate(W01_2, w.PB2bH, w.PB2bL, gid, 16, F32); return; }
  gid -= NG;
  if (gid < 16384) { packGate(W01_1, w.PB1xH, w.PB1xL, gid, 2, F32); return; }
  gid -= 16384;
  if (gid < 8192) {  // PBo (hi only): [w4][ks 0..31][lane][8]
    int lane = gid & 63;
    int rest = gid >> 6;
    int ks = rest & 31;
    int w4 = rest >> 5;
    int q = lane >> 4;
    int d = w4 * 16 + (lane & 15);
    int kb = ks * 32 + q * 8;
    f16 v[8];
#pragma unroll
    for (int i = 0; i < 8; ++i) {
      int k = kb + i;
      float s = (k < 512) ? ldw(l1W, (size_t)d * 512 + k, F32)
                          : ldw(l2W, (size_t)d * 512 + (k - 512), F32);
      v[i] = (f16)s;
    }
    *(f16x8*)(w.PBo + (size_t)gid * 8) = *(f16x8*)v;
    return;
  }
  gid -= 8192;
  if (gid < 2112) {  // z-column weights, cell1 (fp32 exact)
    int i = gid; float s;
    if (i < 512)       s = ldw(U11_1, (size_t)i * 2049 + 2048, F32);
    else if (i < 1024) s = ldw(U11_1, (size_t)(i - 512) * 2049 + 2048, F32);
    else if (i < 1536) s = ldw(U21_1, (size_t)(i - 1024) * 2049 + 2048, F32);
    else if (i < 2048) s = ldw(U21_1, (size_t)(i - 1536) * 2049 + 2048, F32);
    else               s = ldw(W01_1, (size_t)(i - 2048) * 2049 + 2048, F32);
    w.wz1[i] = s; return;
  }
  gid -= 2112;
  if (gid < 2048) {  // z-column weights, cell2
    int i = gid; float s;
    if (i < 512)       s = ldw(U11_2, (size_t)i * 2049 + 2048, F32);
    else if (i < 1024) s = ldw(U11_2, (size_t)(i - 512) * 2049 + 2048, F32);
    else if (i < 1536) s = ldw(W01_2, (size_t)(i - 1024) * 2049 + 2048, F32);
    else               s = ldw(W01_2, (size_t)(i - 1536) * 2049 + 2048, F32);
    w.wz2[i] = s; return;
  }
  gid -= 2048;
  if (gid < 2049) { w.b1f[gid] = ldw(bias1, gid, F32); return; }
  gid -= 2049;
  if (gid < 2049) { w.b2f[gid] = ldw(bias2, gid, F32); return; }
  gid -= 2049;
  if (gid < 64) { w.bof[gid] = ldw(l1b, gid, F32) + ldw(l2b, gid, F32); return; }
}

__global__ __launch_bounds__(256) void init_kernel(WS w)
{
  size_t id = (size_t)blockIdx.x * 256 + threadIdx.x;
  const size_t nw = 131072;  // u32 words per f16 state buffer
  if (id < 2 * nw) {
    u32* p = (id < nw) ? (u32*)w.H1[1] : (u32*)w.H2[1];
    p[id % nw] = 0u;
    return;
  }
  id -= 2 * nw;
  const size_t nf = 131072;
  if (id < 3 * nf) {
    float* p = (id < nf) ? w.c1 : (id < 2 * nf) ? w.c2 : w.h2m;
    p[id % nf] = 0.0f;
    return;
  }
  id -= 3 * nf;
  if (id < 512) {
    ((id < 256) ? w.z1[1] : w.z2[1])[id & 255] = 0.0f;
    return;
  }
  id -= 512;
  if (id < 2048) w.bar[id] = 0;  // barrier + registration state (each replay)
}

// ---------------- output tile: out[b,twrite,:] = h1@l1W^T + h2@l2W^T + bias ----
__device__ __forceinline__ void out_tile(const WS& w, void* __restrict__ out, int F32,
                                         int pq, int twrite, int ot, int w4, int lane,
                                         int lok)
{
  const f16* A1 = w.H1[pq] + (size_t)ot * 16384 + lane * 8;  // hi sections only
  const f16* A2 = w.H2[pq] + (size_t)ot * 16384 + lane * 8;
  const f16* Bo = w.PBo + (size_t)w4 * 16384 + lane * 8;
  f32x4 acc = {0.f, 0.f, 0.f, 0.f};
#pragma unroll
  for (int kb = 0; kb < 4; ++kb) {
    f16x8 a0, a1, a2, a3;
    ld4a(A1 + (kb*4+0)*512, A1 + (kb*4+1)*512, A1 + (kb*4+2)*512, A1 + (kb*4+3)*512,
         a0, a1, a2, a3, lok);
    acc = MFMA(a0, ldf(Bo + (kb*4+0)*512), acc);
    acc = MFMA(a1, ldf(Bo + (kb*4+1)*512), acc);
    acc = MFMA(a2, ldf(Bo + (kb*4+2)*512), acc);
    acc = MFMA(a3, ldf(Bo + (kb*4+3)*512), acc);
  }
#pragma unroll
  for (int kb = 0; kb < 4; ++kb) {
    f16x8 a0, a1, a2, a3;
    ld4a(A2 + (kb*4+0)*512, A2 + (kb*4+1)*512, A2 + (kb*4+2)*512, A2 + (kb*4+3)*512,
         a0, a1, a2, a3, lok);
    acc = MFMA(a0, ldf(Bo + (16+kb*4+0)*512), acc);
    acc = MFMA(a1, ldf(Bo + (16+kb*4+1)*512), acc);
    acc = MFMA(a2, ldf(Bo + (16+kb*4+2)*512), acc);
    acc = MFMA(a3, ldf(Bo + (16+kb*4+3)*512), acc);
  }
  const int q = lane >> 4;
  const int d = w4 * 16 + (lane & 15);
  const float bias = w.bof[d];
#pragma unroll
  for (int r = 0; r < 4; ++r) {
    const int b = ot * 16 + q * 4 + r;
    const size_t idx = ((size_t)b * TT + twrite) * DD + d;
    const float val = acc[r] + bias;
    if (F32) ((float*)out)[idx] = val;
    else     ((u16*)out)[idx] = f2bf(val);
  }
}

// ---------------- z-logit rows (one wave per row, fp64 shuffle-reduce) -------
// s_z1 = h1@wz + z1p*(h2@wz') + x@wz'' + bias  (z1p in {0,1} -> exact)
__device__ __forceinline__ void z1_row(const WS& w, const void* __restrict__ x,
                                       int F32, int t, int pp, int pc, int b, int lane,
                                       int lok)
{
  const int ks = lane >> 2;   // 0..15
  const int qq = lane & 3;    // 0..3
  const int j = ks * 32 + qq * 8;
  const size_t fro = (size_t)(b >> 4) * 16384 + (b & 15) * 8
                   + (size_t)ks * 512 + (size_t)qq * 128;
  const f16* pa = w.H1[pp] + fro;
  const f16* ph = w.H2[pp] + fro;
  f16x8 h8, l8, g8, m8;
  ld4a(pa, pa + 8192, ph, ph + 8192, h8, l8, g8, m8, lok);
  double aa = 0.0, az = 0.0;
#pragma unroll
  for (int i = 0; i < 8; ++i) {
    double ha = (double)(float)h8[i] + (double)(float)l8[i] * (1.0 / 2048.0);
    double hz = (double)(float)g8[i] + (double)(float)m8[i] * (1.0 / 2048.0);
    aa += ha * (double)w.wz1[j + i];
    az += hz * (double)w.wz1[1024 + j + i];
  }
  {  // x part: lane d = lane handles one element
    float xv = ldw(x, ((size_t)b * TT + t) * DD + lane, F32);
    aa += (double)xv * (double)w.wz1[2048 + lane];
  }
#pragma unroll
  for (int off = 32; off; off >>= 1) {
    aa += shfl_down_dbl(aa, off);
    az += shfl_down_dbl(az, off);
  }
  if (lane == 0) {
    const double z1p = (double)ldcf(w.z1[pp] + b);
    float sz = (float)(aa + z1p * az + (double)w.b1f[2048]);
    float zh = (sz + 1.0f) * 0.5f;  // round-half-even(zh) == (zh > 0.5)
    stcf(w.z1[pc] + b, (zh > 0.5f) ? 1.0f : 0.0f);
  }
}

__device__ __forceinline__ void z2_row(const WS& w, int t, int pp, int pc,
                                       int b, int lane, int lok)
{
  const int ks = lane >> 2;
  const int qq = lane & 3;
  const int j = ks * 32 + qq * 8;
  const size_t fro = (size_t)(b >> 4) * 16384 + (b & 15) * 8
                   + (size_t)ks * 512 + (size_t)qq * 128;
  const f16* pa = w.H2[pp] + fro;
  const f16* pb = w.H1[pc] + fro;
  f16x8 h8, l8, h8b, l8b;
  ld4a(pa, pa + 8192, pb, pb + 8192, h8, l8, h8b, l8b, lok);
  double da = 0.0, db = 0.0;
#pragma unroll
  for (int i = 0; i < 8; ++i) {
    double ha = (double)(float)h8[i]  + (double)(float)l8[i]  * (1.0 / 2048.0);
    double hb = (double)(float)h8b[i] + (double)(float)l8b[i] * (1.0 / 2048.0);
    da += ha * (double)w.wz2[j + i];
    db += hb * (double)w.wz2[1024 + j + i];
  }
#pragma unroll
  for (int off = 32; off; off >>= 1) {
    da += shfl_down_dbl(da, off);
    db += shfl_down_dbl(db, off);
  }
  if (lane == 0) {
    const double z1n = (double)ldcf(w.z1[pc] + b);
    float sz = (float)(da + z1n * db + (double)w.b2f[2048]);
    stcf(w.z2[pc] + b, (((sz + 1.0f) * 0.5f) > 0.5f) ? 1.0f : 0.0f);
  }
}

// ---------------- persistent kernel: full 512-step recurrence ----------------
// Grid 256 x 512. Block covers (mtile, 4 J's); waves (Jsub = wv&3, kh = wv>>2).
// Registration discovers XCD layout; LOCAL mode if each XCD hosts exactly 32
// blocks (then mt = 2*xcc + rank/16, Jgrp = rank%16: all column-producers of
// an mtile share one XCD -> sc0 L2-local data path + per-XCD barriers).
__global__ __launch_bounds__(512) void persist(const void* __restrict__ x,
                                               void* __restrict__ out, WS w)
{
  __shared__ f16 sA[16384];   // 32KB: phA = H1[pp]; phB = H1[pc]; ex-overlay
  __shared__ f16 sH2[16384];  // 32KB: H2[pp] (phA stage, phA kh1 + phB kh0); ex-overlay
  __shared__ int sreg[3];     // xcc, rank, ok
  const int F32 = *w.flag;
  const int bid = blockIdx.x;
  const int tid = threadIdx.x;
  const int lane = tid & 63, wv = tid >> 6;
  // ---- XCD registration ----
  if (tid == 0) {
    const int xcc = __builtin_amdgcn_s_getreg((31 << 11) | 20) & 7;  // HW_REG_XCC_ID
    const int rank = __hip_atomic_fetch_add(w.bar + 544 + xcc * 8, 1,
                                            __ATOMIC_RELAXED, __HIP_MEMORY_SCOPE_AGENT);
    sreg[0] = xcc;   // LDS store of returned rank forces vmcnt drain before barrier
    sreg[1] = rank;
  }
  gridbar(w.bar, bid & 7, 1, 0);  // global registration barrier (counts final)
  if (tid == 0) {
    int ok = 1;
#pragma unroll
    for (int i = 0; i < 8; ++i)
      ok &= (__hip_atomic_load(w.bar + 544 + i * 8, __ATOMIC_RELAXED,
                               __HIP_MEMORY_SCOPE_AGENT) == 32);
    sreg[2] = ok;
  }
  __syncthreads();
  const int lok  = sreg[2];
  const int xcc  = sreg[0], rank = sreg[1];
  const int grp  = lok ? xcc : (bid & 7);
  const int mt   = lok ? (2 * xcc + (rank >> 4)) : (bid >> 4);
  const int Jgrp = lok ? (rank & 15) : (bid & 15);
  const int zrow = lok ? (32 * xcc + rank) : bid;
  const bool doOut = lok ? ((rank & 15) < 4) : (bid < 64);
  const int ot   = lok ? mt : (bid >> 2);
  const int w4   = lok ? (rank & 3) : (bid & 3);

  const int Jsub = wv & 3, kh = wv >> 2;
  const int J = Jgrp * 4 + Jsub;
  const int m0 = mt * 16;
  const int q = lane >> 4;
  const int jcol = J * 8 + (lane & 7);
  const bool ilane = (lane & 8) != 0;
  const int r_own = (ilane ? 2 : 0) + kh;
  const int b_own = m0 + q * 4 + r_own;
  const int idx_own = b_own * 512 + jcol;
  const size_t off_own = (size_t)mt * 16384 + (size_t)(jcol >> 5) * 512
                       + ((jcol >> 3) & 3) * 128 + (b_own & 15) * 8 + (jcol & 7);
  const int zrow_lo = m0 + q * 4 + kh;        // merge r = kh
  const int zrow_hi = zrow_lo + 2;            // merge r = 2+kh
  const float b1ff = w.b1f[jcol], b1fi = w.b1f[512 + jcol];
  const float b1fo = w.b1f[1024 + jcol], b1fg = w.b1f[1536 + jcol];
  const float b2ff = w.b2f[jcol], b2fi = w.b2f[512 + jcol];
  const float b2fo = w.b2f[1024 + jcol], b2fg = w.b2f[1536 + jcol];
  const int exw = ((Jsub * 2 + kh) * 64 + lane) * 9;
  const int exr0 = ((Jsub * 2 + 0) * 64 + lane) * 9;
  const int exr1 = ((Jsub * 2 + 1) * 64 + lane) * 9;

  for (int t = 0; t < 512; ++t) {
    const int pc = t & 1, pp = pc ^ 1;
    // ================= phase A: cell 1 =================
    const float z1p_lo = ldcf(w.z1[pp] + zrow_lo);
    const float z1p_hi = ldcf(w.z1[pp] + zrow_hi);
    {  // stage sA <- H1[pp][mt], sH2 <- H2[pp][mt]  (32KB each)
      const f16* ga = w.H1[pp] + (size_t)mt * 16384 + (size_t)tid * 8;
      const f16* gh = w.H2[pp] + (size_t)mt * 16384 + (size_t)tid * 8;
      f16x8 a0, a1, a2, a3;
      ld4a(ga, ga + 4096, ga + 8192, ga + 12288, a0, a1, a2, a3, lok);
      *(f16x8*)(sA + tid * 8)         = a0;
      *(f16x8*)(sA + tid * 8 + 4096)  = a1;
      *(f16x8*)(sA + tid * 8 + 8192)  = a2;
      *(f16x8*)(sA + tid * 8 + 12288) = a3;
      ld4a(gh, gh + 4096, gh + 8192, gh + 12288, a0, a1, a2, a3, lok);
      *(f16x8*)(sH2 + tid * 8)         = a0;
      *(f16x8*)(sH2 + tid * 8 + 4096)  = a1;
      *(f16x8*)(sH2 + tid * 8 + 8192)  = a2;
      *(f16x8*)(sH2 + tid * 8 + 12288) = a3;
    }
    __syncthreads();
    f32x4 hFI = {0.f,0.f,0.f,0.f}, lFI = {0.f,0.f,0.f,0.f};
    f32x4 hOG = {0.f,0.f,0.f,0.f}, lOG = {0.f,0.f,0.f,0.f};
    {  // kh0: h1 @ U11_1 ; kh1: h2 @ U21_1 (unscaled; z1-scale at merge)
      const f16* As = (kh ? sH2 : sA) + lane * 8;
      const f16* BH = (kh ? w.PB1bH : w.PB1aH) + (size_t)J * 16384 + lane * 8;
      const f16* BL = (kh ? w.PB1bL : w.PB1aL) + (size_t)J * 16384 + lane * 8;
#pragma unroll
      for (int k = 0; k < 16; ++k) {
        f16x8 ah = *(const f16x8*)(As + k * 512);
        f16x8 al = *(const f16x8*)(As + (16 + k) * 512);
        f16x8 b0h = ldf(BH + k * 1024), b0l = ldf(BL + k * 1024);
        f16x8 b1h = ldf(BH + k * 1024 + 512), b1l = ldf(BL + k * 1024 + 512);
        hFI = MFMA(ah, b0h, hFI);
        lFI = MFMA(al, b0h, lFI); lFI = MFMA(ah, b0l, lFI);
        hOG = MFMA(ah, b1h, hOG);
        lOG = MFMA(al, b1h, lOG); lOG = MFMA(ah, b1l, lOG);
      }
    }
    if (kh == 0) {  // x_t @ W01_1 (both 32-K chunks; unscaled path)
      const f16* BxH = w.PB1xH + (size_t)J * 2048 + lane * 8;
      const f16* BxL = w.PB1xL + (size_t)J * 2048 + lane * 8;
      const int row = m0 + (lane & 15);
#pragma unroll
      for (int kx = 0; kx < 2; ++kx) {
        const int d = kx * 32 + q * 8;
        const size_t xoff = ((size_t)row * TT + t) * DD + d;
        float xv[8];
        if (F32) {
          const float* px = (const float*)x + xoff;
          float4 r0 = *(const float4*)px;
          float4 r1 = *(const float4*)(px + 4);
          xv[0]=r0.x; xv[1]=r0.y; xv[2]=r0.z; xv[3]=r0.w;
          xv[4]=r1.x; xv[5]=r1.y; xv[6]=r1.z; xv[7]=r1.w;
        } else {
          const u16* px = (const u16*)x + xoff;
          uint4 raw = *(const uint4*)px;
          u32 rr4[4] = {raw.x, raw.y, raw.z, raw.w};
#pragma unroll
          for (int i = 0; i < 4; ++i) {
            xv[2*i]   = bf2f((u16)(rr4[i] & 0xffffu));
            xv[2*i+1] = bf2f((u16)(rr4[i] >> 16));
          }
        }
        f16x8 axh, axl;
#pragma unroll
        for (int i = 0; i < 8; ++i) {
          f16 h = (f16)xv[i];
          axh[i] = h;
          axl[i] = (f16)((xv[i] - (float)h) * SC);
        }
        f16x8 b0h = ldf(BxH + kx * 1024), b0l = ldf(BxL + kx * 1024);
        f16x8 b1h = ldf(BxH + kx * 1024 + 512), b1l = ldf(BxL + kx * 1024 + 512);
        hFI = MFMA(axh, b0h, hFI);
        lFI = MFMA(axl, b0h, lFI); lFI = MFMA(axh, b0l, lFI);
        hOG = MFMA(axh, b1h, hOG);
        lOG = MFMA(axl, b1h, lOG); lOG = MFMA(axh, b1l, lOG);
      }
    }
    __syncthreads();   // all waves done reading sA before ex-overlay
    {
      float* ex = (float*)sA;
#pragma unroll
      for (int r = 0; r < 4; ++r) {
        ex[exw + r]     = hFI[r] + lFI[r] * ISC;
        ex[exw + 4 + r] = hOG[r] + lOG[r] * ISC;
      }
    }
    __syncthreads();
    {
      const float* ex = (const float*)sA;
      const float aFIlo = ex[exr0 + kh]     + z1p_lo * ex[exr1 + kh];
      const float aFIhi = ex[exr0 + 2 + kh] + z1p_hi * ex[exr1 + 2 + kh];
      const float aOGlo = ex[exr0 + 4 + kh] + z1p_lo * ex[exr1 + 4 + kh];
      const float aOGhi = ex[exr0 + 6 + kh] + z1p_hi * ex[exr1 + 6 + kh];
      const float oFIlo = __shfl_xor(aFIlo, 8), oFIhi = __shfl_xor(aFIhi, 8);
      const float oOGlo = __shfl_xor(aOGlo, 8), oOGhi = __shfl_xor(aOGhi, 8);
      // fused cell-1 epilogue (z = z1_prev, z_bottom = 1 -> h = o*tanh(c))
      const float sf = (ilane ? oFIhi : aFIlo) + b1ff;
      const float si = (ilane ? aFIhi : oFIlo) + b1fi;
      const float so = (ilane ? oOGhi : aOGlo) + b1fo;
      const float sg = (ilane ? aOGhi : oOGlo) + b1fg;
      const float f = sigm(sf), i_ = sigm(si), o = sigm(so), g = tanhf(sg);
      const float cold = w.c1[idx_own];
      const float z1p = ilane ? z1p_hi : z1p_lo;
      const float ig = i_ * g;
      const float cn = (z1p != 0.0f) ? ig : (f * cold + ig);
      const float hn = o * tanhf(cn);
      w.c1[idx_own] = cn;
      const f16 hi = (f16)hn;
      const f16 lo = (f16)((hn - (float)hi) * SC);
      st2a(w.H1[pc] + off_own, hi, lok);
      st2a(w.H1[pc] + off_own + 8192, lo, lok);
    }
    if (wv == 7) z1_row(w, x, F32, t, pp, pc, zrow, lane, lok);
    gridbar(w.bar, grp, 2 * t + 2, lok);
    // ================= phase B: cell 2 =================
    const float z1c_lo = ldcf(w.z1[pc] + zrow_lo);
    const float z1c_hi = ldcf(w.z1[pc] + zrow_hi);
    const float z2p_own = ldcf(w.z2[pp] + b_own);
    {  // stage sA <- H1[pc][mt]  (sH2 still holds H2[pp])
      const f16* ga = w.H1[pc] + (size_t)mt * 16384 + (size_t)tid * 8;
      f16x8 a0, a1, a2, a3;
      ld4a(ga, ga + 4096, ga + 8192, ga + 12288, a0, a1, a2, a3, lok);
      *(f16x8*)(sA + tid * 8)         = a0;
      *(f16x8*)(sA + tid * 8 + 4096)  = a1;
      *(f16x8*)(sA + tid * 8 + 8192)  = a2;
      *(f16x8*)(sA + tid * 8 + 12288) = a3;
    }
    __syncthreads();
    f32x4 pFIh = {0.f,0.f,0.f,0.f}, pFIl = {0.f,0.f,0.f,0.f};
    f32x4 pOGh = {0.f,0.f,0.f,0.f}, pOGl = {0.f,0.f,0.f,0.f};
    {  // kh0: h2 @ U11_2 ; kh1: h1_new @ W01_2 (unscaled; z1-scale at merge)
      const f16* As = (kh ? sA : sH2) + lane * 8;
      const f16* BH = (kh ? w.PB2bH : w.PB2aH) + (size_t)J * 16384 + lane * 8;
      const f16* BL = (kh ? w.PB2bL : w.PB2aL) + (size_t)J * 16384 + lane * 8;
#pragma unroll
      for (int k = 0; k < 16; ++k) {
        f16x8 ah = *(const f16x8*)(As + k * 512);
        f16x8 al = *(const f16x8*)(As + (16 + k) * 512);
        f16x8 b0h = ldf(BH + k * 1024), b0l = ldf(BL + k * 1024);
        f16x8 b1h = ldf(BH + k * 1024 + 512), b1l = ldf(BL + k * 1024 + 512);
        pFIh = MFMA(ah, b0h, pFIh);
        pFIl = MFMA(al, b0h, pFIl); pFIl = MFMA(ah, b0l, pFIl);
        pOGh = MFMA(ah, b1h, pOGh);
        pOGl = MFMA(al, b1h, pOGl); pOGl = MFMA(ah, b1l, pOGl);
      }
    }
    __syncthreads();   // all waves done reading sH2 before ex-overlay
    {
      float* ex = (float*)sH2;
#pragma unroll
      for (int r = 0; r < 4; ++r) {
        ex[exw + r]     = pFIh[r] + pFIl[r] * ISC;
        ex[exw + 4 + r] = pOGh[r] + pOGl[r] * ISC;
      }
    }
    __syncthreads();
    {
      const float* ex = (const float*)sH2;
      const float aFIlo = ex[exr0 + kh]     + z1c_lo * ex[exr1 + kh];
      const float aFIhi = ex[exr0 + 2 + kh] + z1c_hi * ex[exr1 + 2 + kh];
      const float aOGlo = ex[exr0 + 4 + kh] + z1c_lo * ex[exr1 + 4 + kh];
      const float aOGhi = ex[exr0 + 6 + kh] + z1c_hi * ex[exr1 + 6 + kh];
      const float oFIlo = __shfl_xor(aFIlo, 8), oFIhi = __shfl_xor(aFIhi, 8);
      const float oOGlo = __shfl_xor(aOGlo, 8), oOGhi = __shfl_xor(aOGhi, 8);
      const float sf = (ilane ? oFIhi : aFIlo) + b2ff;
      const float si = (ilane ? aFIhi : oFIlo) + b2fi;
      const float so = (ilane ? oOGhi : aOGlo) + b2fo;
      const float sg = (ilane ? aOGhi : oOGlo) + b2fg;
      const float f = sigm(sf), i_ = sigm(si), o = sigm(so), g = tanhf(sg);
      const float cold = w.c2[idx_own];
      const float h2old = w.h2m[idx_own];
      const float z1r = ilane ? z1c_hi : z1c_lo;
      const float ig = i_ * g;
      const bool zz = (z2p_own != 0.0f), zb = (z1r != 0.0f);
      const float cn = zz ? ig : (zb ? (f * cold + ig) : cold);  // UPDATE/FLUSH/COPY
      const float th = o * tanhf(cn);
      const float hn = (zz || zb) ? th : h2old;
      w.c2[idx_own] = cn;
      w.h2m[idx_own] = hn;
      const f16 hi = (f16)hn;
      const f16 lo = (f16)((hn - (float)hi) * SC);
      st2a(w.H2[pc] + off_own, hi, lok);
      st2a(w.H2[pc] + off_own + 8192, lo, lok);
    }
    if (wv == 7) z2_row(w, t, pp, pc, zrow, lane, lok);
    if (doOut && wv == 6 && t > 0)
      out_tile(w, out, F32, pp, t - 1, ot, w4, lane, lok);
    gridbar(w.bar, grp, 2 * t + 3, lok);
  }
  // final output row (t = 511, parity 1)
  if (doOut && wv == 6) out_tile(w, out, F32, 1, 511, ot, w4, lane, lok);
}

extern "C" void kernel_launch(void* const* d_in, const int* in_sizes, int n_in,
                              void* d_out, int out_size, void* d_ws, size_t ws_size,
                              hipStream_t stream)
{
  (void)in_sizes; (void)n_in; (void)out_size; (void)ws_size;
  const void* x     = d_in[0];
  const void* U11_1 = d_in[1];
  const void* U21_1 = d_in[2];
  const void* W01_1 = d_in[3];
  const void* bias1 = d_in[4];
  const void* U11_2 = d_in[5];
  const void* W01_2 = d_in[6];
  const void* bias2 = d_in[7];
  const void* l1W   = d_in[8];
  const void* l1b   = d_in[9];
  const void* l2W   = d_in[10];
  const void* l2b   = d_in[11];

  char* base = (char*)d_ws;
  size_t o = 0;
  auto take = [&](size_t bytes) -> char* {
    char* p = base + o;
    o = (o + bytes + 1023) & ~(size_t)1023;
    return p;
  };
  WS w;
  w.PB1aH = (f16*)take(1048576 * 2); w.PB1aL = (f16*)take(1048576 * 2);
  w.PB1bH = (f16*)take(1048576 * 2); w.PB1bL = (f16*)take(1048576 * 2);
  w.PB2aH = (f16*)take(1048576 * 2); w.PB2aL = (f16*)take(1048576 * 2);
  w.PB2bH = (f16*)take(1048576 * 2); w.PB2bL = (f16*)take(1048576 * 2);
  w.PB1xH = (f16*)take(131072 * 2);  w.PB1xL = (f16*)take(131072 * 2);
  w.PBo   = (f16*)take(65536 * 2);
  for (int i = 0; i < 2; ++i) w.H1[i] = (f16*)take(262144 * 2);
  for (int i = 0; i < 2; ++i) w.H2[i] = (f16*)take(262144 * 2);
  w.c1  = (float*)take(131072 * 4);
  w.c2  = (float*)take(131072 * 4);
  w.h2m = (float*)take(131072 * 4);
  w.wz1 = (float*)take(2112 * 4);
  w.wz2 = (float*)take(2048 * 4);
  w.b1f = (float*)take(2049 * 4);
  w.b2f = (float*)take(2049 * 4);
  w.bof = (float*)take(64 * 4);
  for (int i = 0; i < 2; ++i) w.z1[i] = (float*)take(256 * 4);
  for (int i = 0; i < 2; ++i) w.z2[i] = (float*)take(256 * 4);
  w.bar = (int*)take(2048 * 4);
  w.flag = (int*)take(4 * 4);
  // total ~20.5 MB of d_ws

  detect_kernel<<<1, 64, 0, stream>>>((const u16*)x, w.flag);
  pack_kernel<<<(NPACK + 255) / 256, 256, 0, stream>>>(
      U11_1, U21_1, W01_1, bias1, U11_2, W01_2, bias2, l1W, l1b, l2W, l2b, w);
  init_kernel<<<2570, 256, 0, stream>>>(w);
  persist<<<256, 512, 0, stream>>>(x, d_out, w);
}